// Round 1
// baseline (889.460 us; speedup 1.0000x reference)
//
#include <hip/hip_runtime.h>

// Problem constants: v is (N=2, C=3, D=128, H=128, W=128) float32.
// Outputs: transformation (2,3,128,128,128) then disp_vox (2,3,128,128,128),
// concatenated flat in d_out (all float32).
#define DIM   128
#define DHW   (1 << 21)          // 128^3
#define CDHW  (3 * DHW)
#define NCDHW (2 * CDHW)         // one output's element count
#define NVOX  (2 * DHW)          // N * D*H*W

// u0 = v / 4096  (scale cancels when working in voxel units)
__global__ __launch_bounds__(256) void svf_init(const float* __restrict__ v,
                                                float* __restrict__ u) {
    int i = blockIdx.x * blockDim.x + threadIdx.x;
    u[i] = v[i] * (1.0f / 4096.0f);
}

// One squaring step: uout(p) = uin(p) + trilinear_border(uin, p + uin(p))
__global__ __launch_bounds__(256) void svf_step(const float* __restrict__ uin,
                                                float* __restrict__ uout) {
    int idx = blockIdx.x * blockDim.x + threadIdx.x;   // over N*DHW
    int n = idx >> 21;
    int r = idx & (DHW - 1);
    int x = r & 127;
    int y = (r >> 7) & 127;
    int z = r >> 14;

    const float* un = uin + (size_t)n * CDHW;
    float ux = un[r];
    float uy = un[DHW + r];
    float uz = un[2 * DHW + r];

    float gx = (float)x + ux;
    float gy = (float)y + uy;
    float gz = (float)z + uz;

    float fx = floorf(gx), fy = floorf(gy), fz = floorf(gz);
    float wx = gx - fx, wy = gy - fy, wz = gz - fz;

    int x0 = (int)fx, y0 = (int)fy, z0 = (int)fz;
    int x0c = min(max(x0, 0), 127), x1c = min(max(x0 + 1, 0), 127);
    int y0c = min(max(y0, 0), 127), y1c = min(max(y0 + 1, 0), 127);
    int z0c = min(max(z0, 0), 127), z1c = min(max(z0 + 1, 0), 127);

    int zb0 = z0c << 14, zb1 = z1c << 14;
    int yb0 = y0c << 7,  yb1 = y1c << 7;

    int o000 = zb0 + yb0 + x0c;  // (z0,y0,x0)
    int o001 = zb0 + yb0 + x1c;
    int o010 = zb0 + yb1 + x0c;
    int o011 = zb0 + yb1 + x1c;
    int o100 = zb1 + yb0 + x0c;
    int o101 = zb1 + yb0 + x1c;
    int o110 = zb1 + yb1 + x0c;
    int o111 = zb1 + yb1 + x1c;

    float cz0 = 1.0f - wz, cy0 = 1.0f - wy, cx0 = 1.0f - wx;
    float w000 = cz0 * cy0 * cx0;
    float w001 = cz0 * cy0 * wx;
    float w010 = cz0 * wy  * cx0;
    float w011 = cz0 * wy  * wx;
    float w100 = wz  * cy0 * cx0;
    float w101 = wz  * cy0 * wx;
    float w110 = wz  * wy  * cx0;
    float w111 = wz  * wy  * wx;

    float* uon = uout + (size_t)n * CDHW;

    float uc[3] = {ux, uy, uz};
#pragma unroll
    for (int c = 0; c < 3; ++c) {
        const float* ch = un + (size_t)c * DHW;
        float s = w000 * ch[o000] + w001 * ch[o001]
                + w010 * ch[o010] + w011 * ch[o011]
                + w100 * ch[o100] + w101 * ch[o101]
                + w110 * ch[o110] + w111 * ch[o111];
        uon[(size_t)c * DHW + r] = uc[c] + s;
    }
}

// transformation = -1 + (2/127) * (coord + u)
__global__ __launch_bounds__(256) void svf_final(const float* __restrict__ u,
                                                 float* __restrict__ T) {
    int i = blockIdx.x * blockDim.x + threadIdx.x;   // over N*C*DHW
    int r = i & (DHW - 1);
    int c = (i >> 21) % 3;
    int coord = (c == 0) ? (r & 127) : (c == 1) ? ((r >> 7) & 127) : (r >> 14);
    T[i] = -1.0f + (2.0f / 127.0f) * ((float)coord + u[i]);
}

extern "C" void kernel_launch(void* const* d_in, const int* in_sizes, int n_in,
                              void* d_out, int out_size, void* d_ws, size_t ws_size,
                              hipStream_t stream) {
    const float* v = (const float*)d_in[0];
    float* out = (float*)d_out;
    float* T = out;            // first half: transformation (also ping buffer A)
    float* B = out + NCDHW;    // second half: disp_vox (ping buffer B)

    // u0 -> B
    svf_init<<<NCDHW / 256, 256, 0, stream>>>(v, B);

    // 12 squaring steps, ping-ponging B <-> T-region.
    // s even: B -> A(T region); s odd: A -> B. After s=11 (odd), u12 is in B.
    float* bufs[2] = {B, T};
    for (int s = 0; s < 12; ++s) {
        const float* src = bufs[s & 1];
        float* dst = bufs[(s + 1) & 1];
        svf_step<<<NVOX / 256, 256, 0, stream>>>(src, dst);
    }

    // finalize transformation from u12 (in B); B itself is already disp_vox.
    svf_final<<<NCDHW / 256, 256, 0, stream>>>(B, T);
}

// Round 2
// 443.716 us; speedup vs baseline: 2.0046x; 2.0046x over previous
//
#include <hip/hip_runtime.h>

// v: (N=2, C=3, D=128, H=128, W=128) float32.
// d_out: transformation (2,3,128^3) then disp_vox (2,3,128^3), float32, flat.
#define DHW   (1 << 21)          // 128^3
#define CDHW  (3 * DHW)
#define NCDHW (2 * CDHW)         // one output's element count
#define NVOX  (2 * DHW)          // N * D*H*W

struct f3 { float x, y, z; };    // 12B packed, 4B aligned

// u0 = v / 4096, planar -> interleaved
__global__ __launch_bounds__(256) void svf_init(const float* __restrict__ v,
                                                f3* __restrict__ u) {
    int i = blockIdx.x * blockDim.x + threadIdx.x;   // over NVOX
    int n = i >> 21;
    int r = i & (DHW - 1);
    const float* vn = v + (size_t)n * CDHW;
    f3 o;
    o.x = vn[r] * (1.0f / 4096.0f);
    o.y = vn[DHW + r] * (1.0f / 4096.0f);
    o.z = vn[2 * DHW + r] * (1.0f / 4096.0f);
    u[i] = o;
}

// core: u_new(p) = u(p) + trilinear_border(u, p + u(p)), interleaved field
__device__ __forceinline__ f3 step_compute(const f3* __restrict__ un, int r) {
    int x = r & 127;
    int y = (r >> 7) & 127;
    int z = r >> 14;

    f3 uc = un[r];

    float gx = (float)x + uc.x;
    float gy = (float)y + uc.y;
    float gz = (float)z + uc.z;

    float fx = floorf(gx), fy = floorf(gy), fz = floorf(gz);
    float wx = gx - fx, wy = gy - fy, wz = gz - fz;

    int x0 = (int)fx, y0 = (int)fy, z0 = (int)fz;
    int x0c = min(max(x0, 0), 127), x1c = min(max(x0 + 1, 0), 127);
    int y0c = min(max(y0, 0), 127), y1c = min(max(y0 + 1, 0), 127);
    int z0c = min(max(z0, 0), 127), z1c = min(max(z0 + 1, 0), 127);

    int zb0 = z0c << 14, zb1 = z1c << 14;
    int yb0 = y0c << 7,  yb1 = y1c << 7;

    f3 c000 = un[zb0 + yb0 + x0c];
    f3 c001 = un[zb0 + yb0 + x1c];
    f3 c010 = un[zb0 + yb1 + x0c];
    f3 c011 = un[zb0 + yb1 + x1c];
    f3 c100 = un[zb1 + yb0 + x0c];
    f3 c101 = un[zb1 + yb0 + x1c];
    f3 c110 = un[zb1 + yb1 + x0c];
    f3 c111 = un[zb1 + yb1 + x1c];

    float cz0 = 1.0f - wz, cy0 = 1.0f - wy, cx0 = 1.0f - wx;
    float w000 = cz0 * cy0 * cx0;
    float w001 = cz0 * cy0 * wx;
    float w010 = cz0 * wy  * cx0;
    float w011 = cz0 * wy  * wx;
    float w100 = wz  * cy0 * cx0;
    float w101 = wz  * cy0 * wx;
    float w110 = wz  * wy  * cx0;
    float w111 = wz  * wy  * wx;

    f3 o;
    o.x = uc.x + w000 * c000.x + w001 * c001.x + w010 * c010.x + w011 * c011.x
               + w100 * c100.x + w101 * c101.x + w110 * c110.x + w111 * c111.x;
    o.y = uc.y + w000 * c000.y + w001 * c001.y + w010 * c010.y + w011 * c011.y
               + w100 * c100.y + w101 * c101.y + w110 * c110.y + w111 * c111.y;
    o.z = uc.z + w000 * c000.z + w001 * c001.z + w010 * c010.z + w011 * c011.z
               + w100 * c100.z + w101 * c101.z + w110 * c110.z + w111 * c111.z;
    return o;
}

// interleaved -> interleaved
__global__ __launch_bounds__(256) void svf_step(const f3* __restrict__ uin,
                                                f3* __restrict__ uout) {
    int i = blockIdx.x * blockDim.x + threadIdx.x;   // over NVOX
    int n = i >> 21;
    int r = i & (DHW - 1);
    uout[i] = step_compute(uin + (size_t)n * DHW, r);
}

// interleaved -> planar (used as step 11 when no fused path)
__global__ __launch_bounds__(256) void svf_step_planar(const f3* __restrict__ uin,
                                                       float* __restrict__ up) {
    int i = blockIdx.x * blockDim.x + threadIdx.x;
    int n = i >> 21;
    int r = i & (DHW - 1);
    f3 o = step_compute(uin + (size_t)n * DHW, r);
    float* uon = up + (size_t)n * CDHW;
    uon[r] = o.x;
    uon[DHW + r] = o.y;
    uon[2 * DHW + r] = o.z;
}

// interleaved -> both planar outputs (fused step 11 + epilogue)
__global__ __launch_bounds__(256) void svf_step_fused(const f3* __restrict__ uin,
                                                      float* __restrict__ T,
                                                      float* __restrict__ Dp) {
    int i = blockIdx.x * blockDim.x + threadIdx.x;
    int n = i >> 21;
    int r = i & (DHW - 1);
    int x = r & 127;
    int y = (r >> 7) & 127;
    int z = r >> 14;
    f3 o = step_compute(uin + (size_t)n * DHW, r);
    float* Dn = Dp + (size_t)n * CDHW;
    Dn[r] = o.x;
    Dn[DHW + r] = o.y;
    Dn[2 * DHW + r] = o.z;
    float* Tn = T + (size_t)n * CDHW;
    Tn[r] = -1.0f + (2.0f / 127.0f) * ((float)x + o.x);
    Tn[DHW + r] = -1.0f + (2.0f / 127.0f) * ((float)y + o.y);
    Tn[2 * DHW + r] = -1.0f + (2.0f / 127.0f) * ((float)z + o.z);
}

// planar u12 -> transformation
__global__ __launch_bounds__(256) void svf_final(const float* __restrict__ u,
                                                 float* __restrict__ T) {
    int i = blockIdx.x * blockDim.x + threadIdx.x;   // over NCDHW
    int r = i & (DHW - 1);
    int c = (i >> 21) % 3;
    int coord = (c == 0) ? (r & 127) : (c == 1) ? ((r >> 7) & 127) : (r >> 14);
    T[i] = -1.0f + (2.0f / 127.0f) * ((float)coord + u[i]);
}

extern "C" void kernel_launch(void* const* d_in, const int* in_sizes, int n_in,
                              void* d_out, int out_size, void* d_ws, size_t ws_size,
                              hipStream_t stream) {
    const float* v = (const float*)d_in[0];
    float* out = (float*)d_out;
    const int gridV = NVOX / 256;

    const size_t need = (size_t)NVOX * sizeof(f3);   // 50.3 MB
    if (ws_size >= need) {
        // Fused path: ping-pong between A (= T half of d_out) and d_ws.
        f3* A = (f3*)out;
        f3* Wb = (f3*)d_ws;
        svf_init<<<gridV, 256, 0, stream>>>(v, A);
        // s even: A->Wb, s odd: Wb->A; after s=10 u11 is in Wb
        for (int s = 0; s <= 10; ++s) {
            const f3* src = (s & 1) ? Wb : A;
            f3* dst = (s & 1) ? A : Wb;
            svf_step<<<gridV, 256, 0, stream>>>(src, dst);
        }
        svf_step_fused<<<gridV, 256, 0, stream>>>(Wb, out, out + NCDHW);
    } else {
        // In-place path: ping-pong between the two halves of d_out.
        f3* Ai = (f3*)out;            // T half
        f3* Bi = (f3*)(out + NCDHW);  // disp half
        svf_init<<<gridV, 256, 0, stream>>>(v, Bi);
        // s even: Bi->Ai, s odd: Ai->Bi; after s=10 u11 is in Ai
        for (int s = 0; s <= 10; ++s) {
            const f3* src = (s & 1) ? Ai : Bi;
            f3* dst = (s & 1) ? Bi : Ai;
            svf_step<<<gridV, 256, 0, stream>>>(src, dst);
        }
        // step 11: interleaved Ai -> planar u12 into disp half
        svf_step_planar<<<gridV, 256, 0, stream>>>(Ai, out + NCDHW);
        // epilogue: planar u12 -> transformation
        svf_final<<<NCDHW / 256, 256, 0, stream>>>(out + NCDHW, out);
    }
}

// Round 3
// 284.547 us; speedup vs baseline: 3.1259x; 1.5594x over previous
//
#include <hip/hip_runtime.h>
#include <hip/hip_fp16.h>

// v: (N=2, C=3, D=128, H=128, W=128) float32.
// d_out: transformation (2,3,128^3) then disp_vox (2,3,128^3), float32, flat.
#define DHW   (1 << 21)          // 128^3
#define CDHW  (3 * DHW)
#define NCDHW (2 * CDHW)
#define NVOX  (2 * DHW)          // N * D*H*W
#define NBLK  (NVOX / 256)       // 16384 step-kernel blocks

// Displacement field stored as half4 (x,y,z,pad) = uint2 per voxel (8B).

struct F3 { float x, y, z; };

__device__ __forceinline__ int swz_block(int bid) {
    // XCD-chunked bijective swizzle (NBLK % 8 == 0)
    const int chunk = NBLK / 8;
    return (bid & 7) * chunk + (bid >> 3);
}

__device__ __forceinline__ F3 f3lerp(F3 a, F3 b, float w) {
    F3 o;
    o.x = fmaf(w, b.x - a.x, a.x);
    o.y = fmaf(w, b.y - a.y, a.y);
    o.z = fmaf(w, b.z - a.z, a.z);
    return o;
}

// Load corner pair [j, j+1] (16B) and lerp along x immediately.
__device__ __forceinline__ F3 xl(const uint2* __restrict__ p, float w) {
    uint4 q = *(const uint4*)p;          // 8B-aligned dwordx4 (hw-supported)
    float2 axy = __half22float2(*(const __half2*)&q.x);
    float  az  = __low2float(*(const __half2*)&q.y);
    float2 bxy = __half22float2(*(const __half2*)&q.z);
    float  bz  = __low2float(*(const __half2*)&q.w);
    F3 o;
    o.x = fmaf(w, bxy.x - axy.x, axy.x);
    o.y = fmaf(w, bxy.y - axy.y, axy.y);
    o.z = fmaf(w, bz - az, az);
    return o;
}

// u_new(p) = u(p) + trilinear_border(u, p + u(p)); border folded into weights.
__device__ __forceinline__ F3 step_compute(const uint2* __restrict__ un, int r) {
    int x = r & 127, y = (r >> 7) & 127, z = r >> 14;

    uint2 c = un[r];
    float2 cxy = __half22float2(*(const __half2*)&c.x);
    float  ucz = __low2float(*(const __half2*)&c.y);
    float ux = cxy.x, uy = cxy.y, uz = ucz;

    float gx = (float)x + ux, gy = (float)y + uy, gz = (float)z + uz;
    float fx = floorf(gx), fy = floorf(gy), fz = floorf(gz);
    float wx = gx - fx, wy = gy - fy, wz = gz - fz;

    // border clamp -> adjusted weights over a regular [base, base+1] window
    wx = (gx < 0.f) ? 0.f : ((gx >= 127.f) ? 1.f : wx);
    wy = (gy < 0.f) ? 0.f : ((gy >= 127.f) ? 1.f : wy);
    wz = (gz < 0.f) ? 0.f : ((gz >= 127.f) ? 1.f : wz);
    int xb = (int)fminf(fmaxf(fx, 0.f), 126.f);
    int yb = (int)fminf(fmaxf(fy, 0.f), 126.f);
    int zb = (int)fminf(fmaxf(fz, 0.f), 126.f);

    const uint2* p00 = un + ((zb << 14) + (yb << 7) + xb);
    F3 q00 = xl(p00,               wx);   // (zb,   yb  )
    F3 q01 = xl(p00 + 128,         wx);   // (zb,   yb+1)
    F3 q10 = xl(p00 + 16384,       wx);   // (zb+1, yb  )
    F3 q11 = xl(p00 + 16384 + 128, wx);   // (zb+1, yb+1)

    F3 qy0 = f3lerp(q00, q01, wy);
    F3 qy1 = f3lerp(q10, q11, wy);
    F3 s   = f3lerp(qy0, qy1, wz);

    F3 o; o.x = ux + s.x; o.y = uy + s.y; o.z = uz + s.z;
    return o;
}

__device__ __forceinline__ uint2 pack_h4(F3 o) {
    __half2 hxy = __float22half2_rn(make_float2(o.x, o.y));
    __half2 hz  = __float22half2_rn(make_float2(o.z, 0.f));
    uint2 w;
    w.x = *(const unsigned int*)&hxy;
    w.y = *(const unsigned int*)&hz;
    return w;
}

// u0 = v / 4096, planar f32 -> interleaved half4
__global__ __launch_bounds__(256) void svf_init(const float* __restrict__ v,
                                                uint2* __restrict__ u) {
    int i = blockIdx.x * blockDim.x + threadIdx.x;   // over NVOX
    int n = i >> 21, r = i & (DHW - 1);
    const float* vn = v + (size_t)n * CDHW;
    F3 o;
    o.x = vn[r] * (1.0f / 4096.0f);
    o.y = vn[DHW + r] * (1.0f / 4096.0f);
    o.z = vn[2 * DHW + r] * (1.0f / 4096.0f);
    u[i] = pack_h4(o);
}

// interleaved half4 -> interleaved half4
__global__ __launch_bounds__(256) void svf_step(const uint2* __restrict__ uin,
                                                uint2* __restrict__ uout) {
    int i = swz_block(blockIdx.x) * 256 + threadIdx.x;   // over NVOX
    int n = i >> 21, r = i & (DHW - 1);
    uout[i] = pack_h4(step_compute(uin + (size_t)n * DHW, r));
}

// final step fused with epilogue: half4 u11 -> planar f32 T and disp_vox
__global__ __launch_bounds__(256) void svf_fused(const uint2* __restrict__ uin,
                                                 float* __restrict__ T,
                                                 float* __restrict__ Dp) {
    int i = swz_block(blockIdx.x) * 256 + threadIdx.x;
    int n = i >> 21, r = i & (DHW - 1);
    int x = r & 127, y = (r >> 7) & 127, z = r >> 14;
    F3 o = step_compute(uin + (size_t)n * DHW, r);
    float* Dn = Dp + (size_t)n * CDHW;
    Dn[r] = o.x;
    Dn[DHW + r] = o.y;
    Dn[2 * DHW + r] = o.z;
    float* Tn = T + (size_t)n * CDHW;
    Tn[r]           = -1.0f + (2.0f / 127.0f) * ((float)x + o.x);
    Tn[DHW + r]     = -1.0f + (2.0f / 127.0f) * ((float)y + o.y);
    Tn[2 * DHW + r] = -1.0f + (2.0f / 127.0f) * ((float)z + o.z);
}

// fallback: half4 -> planar f32 (step 11 without fusion)
__global__ __launch_bounds__(256) void svf_step_planar(const uint2* __restrict__ uin,
                                                       float* __restrict__ up) {
    int i = blockIdx.x * blockDim.x + threadIdx.x;
    int n = i >> 21, r = i & (DHW - 1);
    F3 o = step_compute(uin + (size_t)n * DHW, r);
    float* uon = up + (size_t)n * CDHW;
    uon[r] = o.x;
    uon[DHW + r] = o.y;
    uon[2 * DHW + r] = o.z;
}

// fallback epilogue: planar u12 -> transformation
__global__ __launch_bounds__(256) void svf_final(const float* __restrict__ u,
                                                 float* __restrict__ T) {
    int i = blockIdx.x * blockDim.x + threadIdx.x;   // over NCDHW
    int r = i & (DHW - 1);
    int c = (i >> 21) % 3;
    int coord = (c == 0) ? (r & 127) : (c == 1) ? ((r >> 7) & 127) : (r >> 14);
    T[i] = -1.0f + (2.0f / 127.0f) * ((float)coord + u[i]);
}

extern "C" void kernel_launch(void* const* d_in, const int* in_sizes, int n_in,
                              void* d_out, int out_size, void* d_ws, size_t ws_size,
                              hipStream_t stream) {
    const float* v = (const float*)d_in[0];
    float* out = (float*)d_out;
    const size_t bufbytes = (size_t)NVOX * 8;   // 33.5 MB

    if (ws_size >= bufbytes) {
        // A = T-half of d_out (as half4 buffer), B = d_ws.
        uint2* A = (uint2*)out;
        uint2* B = (uint2*)d_ws;
        svf_init<<<NBLK, 256, 0, stream>>>(v, A);
        // 11 ping-pong steps (s=0..10): even A->B, odd B->A; u11 ends in B.
        for (int s = 0; s <= 10; ++s) {
            const uint2* src = (s & 1) ? B : A;
            uint2* dst = (s & 1) ? A : B;
            svf_step<<<NBLK, 256, 0, stream>>>(src, dst);
        }
        // step 11 fused with epilogue: B (ws) -> both planar f32 outputs.
        svf_fused<<<NBLK, 256, 0, stream>>>(B, out, out + NCDHW);
    } else {
        // No usable ws: buffers inside d_out halves (each half 50.3MB > 33.5MB).
        uint2* A = (uint2*)out;            // T half
        uint2* B = (uint2*)(out + NCDHW);  // disp half
        svf_init<<<NBLK, 256, 0, stream>>>(v, B);
        // s even: B->A, s odd: A->B; after s=10, u11 in A (T half).
        for (int s = 0; s <= 10; ++s) {
            const uint2* src = (s & 1) ? A : B;
            uint2* dst = (s & 1) ? B : A;
            svf_step<<<NBLK, 256, 0, stream>>>(src, dst);
        }
        // step 11: A -> planar f32 u12 into disp half (no overlap with A).
        svf_step_planar<<<NBLK, 256, 0, stream>>>(A, out + NCDHW);
        // epilogue: disp half -> transformation half.
        svf_final<<<NCDHW / 256, 256, 0, stream>>>(out + NCDHW, out);
    }
}